// Round 8
// baseline (535.895 us; speedup 1.0000x reference)
//
#include <hip/hip_runtime.h>
#include <hip/hip_bf16.h>

// Conv2d B=32 IC=128 112x112 -> OC=256, K=3, s=2, p=1 (OH=OW=56).
// Round 8: fused implicit GEMM (r7 skeleton, verified mappings) with a
// depth-3 software pipeline:
//   - ALL staging reg-based (W: 4x dwordx4 -> ds_write_b128, wave-self-
//     contained; X: 8 scalar f32 -> cvt_pk -> one 16B ds_write). Compiler
//     tracks every VMEM op via register deps -> counted vmcnt, no drains.
//   - raw s_barrier + lgkmcnt(0) + sched_barrier(0) per phase (no vmcnt(0)
//     drain), 4 LDS buffers, phase s: issue(s+3) / lds-write(s+1) / mfma(s).
//   - 36-phase loop fully unrolled -> all buffer indices literal.

#define B_    32
#define IC_   128
#define H_    112
#define W_    112
#define HW_   (H_ * W_)
#define OC_   256
#define NPIX  (B_ * 56 * 56)              // 100352
#define NTILE (NPIX / 64)                 // 1568
#define WT2_BYTES ((size_t)36 * 16384)    // 589,824

typedef __attribute__((ext_vector_type(8))) short bf16x8;
typedef __attribute__((ext_vector_type(4))) float f32x4;

static __device__ __forceinline__ unsigned f2bf_u(float f) {
  union { float f; unsigned u; } v; v.f = f;
  return (v.u + 0x7FFF + ((v.u >> 16) & 1)) >> 16;   // RNE; inputs finite
}

static __device__ __forceinline__ unsigned pk_bf16(float a, float b) {
  union { __hip_bfloat162 h; unsigned u; } c;
  c.h = __float22bfloat162_rn(float2{a, b});          // v_cvt_pk_bf16_f32
  return c.u;
}

// ---------------- k2: w -> wt2[step][q][oc][8] bf16 ----------------
__global__ __launch_bounds__(256) void wtrans2_kernel(
    const float* __restrict__ w, unsigned short* __restrict__ wt2) {
  const int t  = blockIdx.x * 256 + threadIdx.x;   // oc*128 + ic
  const int oc = t >> 7;
  const int ic = t & 127;
  const int icc = ic >> 5, q = (ic >> 3) & 3, e = ic & 7;
  const float* ws = w + (size_t)t * 9;             // w[oc][ic][*]
#pragma unroll
  for (int tap = 0; tap < 9; ++tap) {
    const int step = tap * 4 + icc;
    wt2[((size_t)(step * 4 + q) * 256 + oc) * 8 + e] =
        (unsigned short)f2bf_u(ws[tap]);
  }
}

// ---------------- k3: fused conv MFMA, depth-3 pipeline ----------------
__global__ __launch_bounds__(256, 2) void conv_fused_kernel(
    const float* __restrict__ x, const unsigned short* __restrict__ wt2,
    const float* __restrict__ bias, float* __restrict__ out) {
  __shared__ unsigned short Wl[4][8192];  // [buf][q][256 oc][8ic] 16KB each
  __shared__ unsigned short Xl[4][2048];  // [buf][q][64 pix][8ic]  4KB each

  const int tid = threadIdx.x, wav = tid >> 6, lane = tid & 63;

  // XCD-chunk swizzle: 1568 = 8*196, bijective.
  const int bid = blockIdx.x;
  const int pt  = (bid & 7) * (NTILE / 8) + (bid >> 3);
  const int p0  = pt * 64;
  const int b   = p0 / 3136;               // 64 | 3136: block never crosses b
  const int q0  = p0 - b * 3136;

  // Per-thread pixel (lane = pixel within tile; fixed for whole K-loop).
  const int pixq = q0 + lane;
  const int oh = pixq / 56, ow = pixq - oh * 56;
  const int ih0 = 2 * oh - 1, iw0 = 2 * ow - 1;    // only -1 can be OOB
  const int boff = ih0 * W_ + iw0;
  const float* xpl = x + (size_t)b * IC_ * HW_;

  unsigned mtap = 0;                        // per-tap validity bitmask
#pragma unroll
  for (int kh = 0; kh < 3; ++kh)
#pragma unroll
    for (int kw = 0; kw < 3; ++kw)
      if (ih0 + kh >= 0 && iw0 + kw >= 0) mtap |= 1u << (kh * 3 + kw);

  const int l15 = lane & 15, lg = lane >> 4;
  const char* wsrc = reinterpret_cast<const char*>(wt2) + wav * 1024 + lane * 16;

  auto loadX = [&](int s, float* v) {       // 8 coalesced f32 loads -> regs
    const int tap = s >> 2, icc = s & 3;
    const int kh = tap / 3, kw = tap - kh * 3;
    const bool m = (mtap >> tap) & 1;
    const int o = boff + kh * W_ + kw + (icc * 32 + wav * 8) * HW_;
#pragma unroll
    for (int k = 0; k < 8; ++k)
      v[k] = m ? xpl[o + k * HW_] : 0.f;
  };
  auto loadW = [&](int s, uint4* vw) {      // 64B/lane -> regs
    const char* src = wsrc + (size_t)s * 16384;
#pragma unroll
    for (int i = 0; i < 4; ++i)
      vw[i] = *reinterpret_cast<const uint4*>(src + i * 4096);
  };
  auto writeX = [&](const float* v, int buf) {   // pack + one 16B LDS write
    uint4 p;
    p.x = pk_bf16(v[0], v[1]);
    p.y = pk_bf16(v[2], v[3]);
    p.z = pk_bf16(v[4], v[5]);
    p.w = pk_bf16(v[6], v[7]);
    *reinterpret_cast<uint4*>(
        reinterpret_cast<char*>(&Xl[buf][0]) + wav * 1024 + lane * 16) = p;
  };
  auto writeW = [&](const uint4* vw, int buf) {  // 4x ds_write_b128, own wave
    char* dst = reinterpret_cast<char*>(&Wl[buf][0]) + wav * 1024 + lane * 16;
#pragma unroll
    for (int i = 0; i < 4; ++i)
      *reinterpret_cast<uint4*>(dst + i * 4096) = vw[i];
  };

  f32x4 acc[4][4] = {};

  auto compute = [&](int buf) {
    bf16x8 af[4], bx[4];
    const unsigned short* wb  = &Wl[buf][0] + lg * 2048;  // q stride 4KB
    const unsigned short* xb2 = &Xl[buf][0] + lg * 512;   // q stride 1KB
#pragma unroll
    for (int mi = 0; mi < 4; ++mi)
      af[mi] = *reinterpret_cast<const bf16x8*>(
          wb + (wav * 64 + mi * 16 + l15) * 8);
#pragma unroll
    for (int ni = 0; ni < 4; ++ni)
      bx[ni] = *reinterpret_cast<const bf16x8*>(xb2 + (ni * 16 + l15) * 8);
#pragma unroll
    for (int mi = 0; mi < 4; ++mi)
#pragma unroll
      for (int ni = 0; ni < 4; ++ni)
        acc[mi][ni] = __builtin_amdgcn_mfma_f32_16x16x32_bf16(
            af[mi], bx[ni], acc[mi][ni], 0, 0, 0);
  };

  float vx[4][8];
  uint4 vw[4][4];

  // Prologue: issue steps 0..2, LDS-commit step 0.
  loadX(0, vx[0]); loadW(0, vw[0]);
  loadX(1, vx[1]); loadW(1, vw[1]);
  loadX(2, vx[2]); loadW(2, vw[2]);
  writeX(vx[0], 0); writeW(vw[0], 0);
  asm volatile("s_waitcnt lgkmcnt(0)" ::: "memory");
  __builtin_amdgcn_sched_barrier(0);
  __builtin_amdgcn_s_barrier();
  __builtin_amdgcn_sched_barrier(0);

  // Steady state: phase s issues s+3, LDS-commits s+1, computes s.
  // Fully unrolled (36 const-trip) -> all (s+k)&3 indices are literals.
#pragma unroll
  for (int s = 0; s < 36; ++s) {
    if (s + 3 < 36) { loadX(s + 3, vx[(s + 3) & 3]); loadW(s + 3, vw[(s + 3) & 3]); }
    if (s + 1 < 36) { writeX(vx[(s + 1) & 3], (s + 1) & 3); writeW(vw[(s + 1) & 3], (s + 1) & 3); }
    asm volatile("s_waitcnt lgkmcnt(0)" ::: "memory");
    __builtin_amdgcn_sched_barrier(0);
    __builtin_amdgcn_s_barrier();
    __builtin_amdgcn_sched_barrier(0);
    compute(s & 3);
  }

  // Epilogue: lanes sweep pixels -> coalesced stores.
#pragma unroll
  for (int mi = 0; mi < 4; ++mi) {
#pragma unroll
    for (int j = 0; j < 4; ++j) {
      const int oc = wav * 64 + mi * 16 + lg * 4 + j;
      const float bv = bias[oc];
#pragma unroll
      for (int ni = 0; ni < 4; ++ni) {
        const int qp = q0 + ni * 16 + l15;
        out[((size_t)b * OC_ + oc) * 3136 + qp] = acc[mi][ni][j] + bv;
      }
    }
  }
}

// ---------------- fallback: fp32 direct conv ----------------
__global__ __launch_bounds__(256) void conv2d_f32_kernel(
    const float* __restrict__ x, const float* __restrict__ w,
    const float* __restrict__ bias, float* __restrict__ out) {
  __shared__ float wlds[IC_ * 9][8];
  const int b   = blockIdx.z;
  const int oc0 = blockIdx.y * 8;
  const float* wsrc = w + (size_t)oc0 * (IC_ * 9);
  for (int i = threadIdx.x; i < IC_ * 9 * 8; i += 256) {
    const int j = i / (IC_ * 9);
    const int t = i - j * (IC_ * 9);
    wlds[t][j] = wsrc[(size_t)j * (IC_ * 9) + t];
  }
  __syncthreads();
  const int p  = blockIdx.x * 256 + threadIdx.x;
  const int ow = p % 56;
  const int oh = p / 56;
  const bool pv = (oh < 56);
  const int ih0 = 2 * oh - 1;
  const int iw0 = 2 * ow - 1;
  const float* xb = x + (size_t)b * IC_ * HW_ + (ptrdiff_t)ih0 * W_ + iw0;
  float acc[8];
#pragma unroll
  for (int j = 0; j < 8; ++j) acc[j] = 0.f;
  for (int ic = 0; ic < IC_; ++ic) {
    const float* xc = xb + (size_t)ic * HW_;
#pragma unroll
    for (int kh = 0; kh < 3; ++kh) {
      const bool hv = pv && ((ih0 + kh) >= 0);
#pragma unroll
      for (int kw = 0; kw < 3; ++kw) {
        const bool v = hv && ((iw0 + kw) >= 0);
        const float xv = v ? xc[kh * W_ + kw] : 0.f;
        const int t = ic * 9 + kh * 3 + kw;
        const float4 w0 = *reinterpret_cast<const float4*>(&wlds[t][0]);
        const float4 w1 = *reinterpret_cast<const float4*>(&wlds[t][4]);
        acc[0] = fmaf(xv, w0.x, acc[0]); acc[1] = fmaf(xv, w0.y, acc[1]);
        acc[2] = fmaf(xv, w0.z, acc[2]); acc[3] = fmaf(xv, w0.w, acc[3]);
        acc[4] = fmaf(xv, w1.x, acc[4]); acc[5] = fmaf(xv, w1.y, acc[5]);
        acc[6] = fmaf(xv, w1.z, acc[6]); acc[7] = fmaf(xv, w1.w, acc[7]);
      }
    }
  }
  if (pv) {
#pragma unroll
    for (int j = 0; j < 8; ++j)
      out[(((size_t)(b * OC_ + oc0 + j)) * 56 + oh) * 56 + ow] =
          acc[j] + bias[oc0 + j];
  }
}

extern "C" void kernel_launch(void* const* d_in, const int* in_sizes, int n_in,
                              void* d_out, int out_size, void* d_ws, size_t ws_size,
                              hipStream_t stream) {
  const float* x    = (const float*)d_in[0];
  const float* w    = (const float*)d_in[1];
  const float* bias = (const float*)d_in[2];
  float* out        = (float*)d_out;

  if (ws_size >= WT2_BYTES) {
    unsigned short* wt2 = (unsigned short*)d_ws;
    wtrans2_kernel<<<128, 256, 0, stream>>>(w, wt2);
    conv_fused_kernel<<<NTILE, 256, 0, stream>>>(x, wt2, bias, out);
  } else {
    conv2d_f32_kernel<<<dim3(13, OC_ / 8, B_), 256, 0, stream>>>(x, w, bias, out);
  }
}

// Round 9
// 169.206 us; speedup vs baseline: 3.1671x; 3.1671x over previous
//
#include <hip/hip_runtime.h>
#include <hip/hip_bf16.h>
#include <type_traits>

// Conv2d B=32 IC=128 112x112 -> OC=256, K=3, s=2, p=1 (OH=OW=56).
// Round 9: r8's depth-3 fused pipeline, scratch-proofed:
//   - register slots are NAMED f32x8 / WReg{4x uint4} values; slot and LDS
//     buffer selection via constexpr-folded ternaries in template<K> phases
//     (r8's 36-trip #pragma unroll was ignored -> runtime idx -> scratch:
//      VGPR 96, 986MB WRITE_SIZE of spill traffic, MfmaUtil 3.9%).
//   - 36 phases = 3 x [PH(0)..PH(11)]  (12 = lcm(3 reg slots, 4 LDS bufs)).
//   - X loads branchless: clamped addr + select (no divergence, no OOB).

#define B_    32
#define IC_   128
#define H_    112
#define W_    112
#define HW_   (H_ * W_)
#define OC_   256
#define NPIX  (B_ * 56 * 56)              // 100352
#define NTILE (NPIX / 64)                 // 1568
#define WT2_BYTES ((size_t)36 * 16384)    // 589,824

typedef __attribute__((ext_vector_type(8))) short bf16x8;
typedef __attribute__((ext_vector_type(8))) float f32x8;
typedef __attribute__((ext_vector_type(4))) float f32x4;

struct WReg { uint4 a, b, c, d; };

static __device__ __forceinline__ unsigned f2bf_u(float f) {
  union { float f; unsigned u; } v; v.f = f;
  return (v.u + 0x7FFF + ((v.u >> 16) & 1)) >> 16;   // RNE; inputs finite
}

static __device__ __forceinline__ unsigned pk_bf16(float a, float b) {
  union { __hip_bfloat162 h; unsigned u; } c;
  c.h = __float22bfloat162_rn(float2{a, b});          // v_cvt_pk_bf16_f32
  return c.u;
}

// ---------------- k2: w -> wt2[step][q][oc][8] bf16 ----------------
__global__ __launch_bounds__(256) void wtrans2_kernel(
    const float* __restrict__ w, unsigned short* __restrict__ wt2) {
  const int t  = blockIdx.x * 256 + threadIdx.x;   // oc*128 + ic
  const int oc = t >> 7;
  const int ic = t & 127;
  const int icc = ic >> 5, q = (ic >> 3) & 3, e = ic & 7;
  const float* ws = w + (size_t)t * 9;             // w[oc][ic][*]
#pragma unroll
  for (int tap = 0; tap < 9; ++tap) {
    const int step = tap * 4 + icc;
    wt2[((size_t)(step * 4 + q) * 256 + oc) * 8 + e] =
        (unsigned short)f2bf_u(ws[tap]);
  }
}

// ---------------- k3: fused conv MFMA, depth-3 pipeline ----------------
__global__ __launch_bounds__(256, 2) void conv_fused_kernel(
    const float* __restrict__ x, const unsigned short* __restrict__ wt2,
    const float* __restrict__ bias, float* __restrict__ out) {
  __shared__ unsigned short Wl[4][8192];  // [buf][q][256 oc][8ic] 16KB each
  __shared__ unsigned short Xl[4][2048];  // [buf][q][64 pix][8ic]  4KB each

  const int tid = threadIdx.x, wav = tid >> 6, lane = tid & 63;

  // XCD-chunk swizzle: 1568 = 8*196, bijective.
  const int bid = blockIdx.x;
  const int pt  = (bid & 7) * (NTILE / 8) + (bid >> 3);
  const int p0  = pt * 64;
  const int b   = p0 / 3136;               // 64 | 3136: block never crosses b
  const int q0  = p0 - b * 3136;

  const int pixq = q0 + lane;
  const int oh = pixq / 56, ow = pixq - oh * 56;
  const int ih0 = 2 * oh - 1, iw0 = 2 * ow - 1;    // only -1 can be OOB
  const int boff = ih0 * W_ + iw0;
  const float* xpl = x + (size_t)b * IC_ * HW_;

  unsigned mtap = 0;                        // per-tap validity bitmask
#pragma unroll
  for (int kh = 0; kh < 3; ++kh)
#pragma unroll
    for (int kw = 0; kw < 3; ++kw)
      if (ih0 + kh >= 0 && iw0 + kw >= 0) mtap |= 1u << (kh * 3 + kw);

  const int l15 = lane & 15, lg = lane >> 4;
  const char* wsrc = reinterpret_cast<const char*>(wt2) + wav * 1024 + lane * 16;

  auto loadX = [&](int s) -> f32x8 {        // 8 coalesced f32 loads -> regs
    const int tap = s >> 2, icc = s & 3;
    const int kh = tap / 3, kw = tap - kh * 3;
    const bool m = (mtap >> tap) & 1;
    const int o  = boff + kh * W_ + kw + (icc * 32 + wav * 8) * HW_;
    const int ob = m ? o : (icc * 32 + wav * 8) * HW_;   // safe in-bounds addr
    f32x8 v;
#pragma unroll
    for (int k = 0; k < 8; ++k) {
      const float t = xpl[ob + k * HW_];
      v[k] = m ? t : 0.f;
    }
    return v;
  };
  auto loadW = [&](int s) -> WReg {         // 64B/lane -> regs
    const char* src = wsrc + (size_t)s * 16384;
    WReg r;
    r.a = *reinterpret_cast<const uint4*>(src);
    r.b = *reinterpret_cast<const uint4*>(src + 4096);
    r.c = *reinterpret_cast<const uint4*>(src + 8192);
    r.d = *reinterpret_cast<const uint4*>(src + 12288);
    return r;
  };
  auto writeX = [&](const f32x8& v, int buf) {   // pack + one 16B LDS write
    uint4 p;
    p.x = pk_bf16(v[0], v[1]);
    p.y = pk_bf16(v[2], v[3]);
    p.z = pk_bf16(v[4], v[5]);
    p.w = pk_bf16(v[6], v[7]);
    *reinterpret_cast<uint4*>(
        reinterpret_cast<char*>(&Xl[buf][0]) + wav * 1024 + lane * 16) = p;
  };
  auto writeW = [&](const WReg& r, int buf) {    // 4x ds_write_b128, own wave
    char* dst = reinterpret_cast<char*>(&Wl[buf][0]) + wav * 1024 + lane * 16;
    *reinterpret_cast<uint4*>(dst)         = r.a;
    *reinterpret_cast<uint4*>(dst + 4096)  = r.b;
    *reinterpret_cast<uint4*>(dst + 8192)  = r.c;
    *reinterpret_cast<uint4*>(dst + 12288) = r.d;
  };

  f32x4 acc[4][4] = {};

  auto compute = [&](int buf) {
    bf16x8 af[4], bx[4];
    const unsigned short* wb  = &Wl[buf][0] + lg * 2048;  // q stride 4KB
    const unsigned short* xb2 = &Xl[buf][0] + lg * 512;   // q stride 1KB
#pragma unroll
    for (int mi = 0; mi < 4; ++mi)
      af[mi] = *reinterpret_cast<const bf16x8*>(
          wb + (wav * 64 + mi * 16 + l15) * 8);
#pragma unroll
    for (int ni = 0; ni < 4; ++ni)
      bx[ni] = *reinterpret_cast<const bf16x8*>(xb2 + (ni * 16 + l15) * 8);
#pragma unroll
    for (int mi = 0; mi < 4; ++mi)
#pragma unroll
      for (int ni = 0; ni < 4; ++ni)
        acc[mi][ni] = __builtin_amdgcn_mfma_f32_16x16x32_bf16(
            af[mi], bx[ni], acc[mi][ni], 0, 0, 0);
  };

  // Three named register slots; step t lives in slot t%3, LDS buf t&3.
  f32x8 xa, xb_, xc;
  WReg  wa, wb_, wc;

  // Prologue: issue steps 0..2, LDS-commit step 0 into buf 0.
  xa = loadX(0); wa = loadW(0);
  xb_ = loadX(1); wb_ = loadW(1);
  xc = loadX(2); wc = loadW(2);
  writeX(xa, 0); writeW(wa, 0);
  asm volatile("s_waitcnt lgkmcnt(0)" ::: "memory");
  __builtin_amdgcn_sched_barrier(0);
  __builtin_amdgcn_s_barrier();
  __builtin_amdgcn_sched_barrier(0);

  // Phase K of macro-block sb (sb = 0,12,24; s = sb+K):
  //   issue loads s+3 into slot K%3 (stale: step s committed last phase),
  //   LDS-commit step s+1 from slot (K+1)%3 into buf (K+1)&3,
  //   fence, barrier, MFMA on buf K&3.
  auto phase = [&](auto KC, int sb) {
    constexpr int K = decltype(KC)::value;
    const int s = sb + K;
    f32x8& xn = (K % 3 == 0) ? xa : (K % 3 == 1) ? xb_ : xc;
    WReg&  wn = (K % 3 == 0) ? wa : (K % 3 == 1) ? wb_ : wc;
    f32x8& xm = ((K + 1) % 3 == 0) ? xa : ((K + 1) % 3 == 1) ? xb_ : xc;
    WReg&  wm = ((K + 1) % 3 == 0) ? wa : ((K + 1) % 3 == 1) ? wb_ : wc;
    if (s + 3 < 36) { xn = loadX(s + 3); wn = loadW(s + 3); }
    if (s + 1 < 36) { writeX(xm, (K + 1) & 3); writeW(wm, (K + 1) & 3); }
    asm volatile("s_waitcnt lgkmcnt(0)" ::: "memory");
    __builtin_amdgcn_sched_barrier(0);
    __builtin_amdgcn_s_barrier();
    __builtin_amdgcn_sched_barrier(0);
    compute(K & 3);
  };

#define PH(K) phase(std::integral_constant<int, K>{}, sb)
  for (int sb = 0; sb < 36; sb += 12) {
    PH(0); PH(1); PH(2); PH(3); PH(4); PH(5);
    PH(6); PH(7); PH(8); PH(9); PH(10); PH(11);
  }
#undef PH

  // Epilogue: lanes sweep pixels -> coalesced stores.
#pragma unroll
  for (int mi = 0; mi < 4; ++mi) {
#pragma unroll
    for (int j = 0; j < 4; ++j) {
      const int oc = wav * 64 + mi * 16 + lg * 4 + j;
      const float bv = bias[oc];
#pragma unroll
      for (int ni = 0; ni < 4; ++ni) {
        const int qp = q0 + ni * 16 + l15;
        out[((size_t)b * OC_ + oc) * 3136 + qp] = acc[mi][ni][j] + bv;
      }
    }
  }
}

// ---------------- fallback: fp32 direct conv ----------------
__global__ __launch_bounds__(256) void conv2d_f32_kernel(
    const float* __restrict__ x, const float* __restrict__ w,
    const float* __restrict__ bias, float* __restrict__ out) {
  __shared__ float wlds[IC_ * 9][8];
  const int b   = blockIdx.z;
  const int oc0 = blockIdx.y * 8;
  const float* wsrc = w + (size_t)oc0 * (IC_ * 9);
  for (int i = threadIdx.x; i < IC_ * 9 * 8; i += 256) {
    const int j = i / (IC_ * 9);
    const int t = i - j * (IC_ * 9);
    wlds[t][j] = wsrc[(size_t)j * (IC_ * 9) + t];
  }
  __syncthreads();
  const int p  = blockIdx.x * 256 + threadIdx.x;
  const int ow = p % 56;
  const int oh = p / 56;
  const bool pv = (oh < 56);
  const int ih0 = 2 * oh - 1;
  const int iw0 = 2 * ow - 1;
  const float* xb = x + (size_t)b * IC_ * HW_ + (ptrdiff_t)ih0 * W_ + iw0;
  float acc[8];
#pragma unroll
  for (int j = 0; j < 8; ++j) acc[j] = 0.f;
  for (int ic = 0; ic < IC_; ++ic) {
    const float* xc = xb + (size_t)ic * HW_;
#pragma unroll
    for (int kh = 0; kh < 3; ++kh) {
      const bool hv = pv && ((ih0 + kh) >= 0);
#pragma unroll
      for (int kw = 0; kw < 3; ++kw) {
        const bool v = hv && ((iw0 + kw) >= 0);
        const float xv = v ? xc[kh * W_ + kw] : 0.f;
        const int t = ic * 9 + kh * 3 + kw;
        const float4 w0 = *reinterpret_cast<const float4*>(&wlds[t][0]);
        const float4 w1 = *reinterpret_cast<const float4*>(&wlds[t][4]);
        acc[0] = fmaf(xv, w0.x, acc[0]); acc[1] = fmaf(xv, w0.y, acc[1]);
        acc[2] = fmaf(xv, w0.z, acc[2]); acc[3] = fmaf(xv, w0.w, acc[3]);
        acc[4] = fmaf(xv, w1.x, acc[4]); acc[5] = fmaf(xv, w1.y, acc[5]);
        acc[6] = fmaf(xv, w1.z, acc[6]); acc[7] = fmaf(xv, w1.w, acc[7]);
      }
    }
  }
  if (pv) {
#pragma unroll
    for (int j = 0; j < 8; ++j)
      out[(((size_t)(b * OC_ + oc0 + j)) * 56 + oh) * 56 + ow] =
          acc[j] + bias[oc0 + j];
  }
}

extern "C" void kernel_launch(void* const* d_in, const int* in_sizes, int n_in,
                              void* d_out, int out_size, void* d_ws, size_t ws_size,
                              hipStream_t stream) {
  const float* x    = (const float*)d_in[0];
  const float* w    = (const float*)d_in[1];
  const float* bias = (const float*)d_in[2];
  float* out        = (float*)d_out;

  if (ws_size >= WT2_BYTES) {
    unsigned short* wt2 = (unsigned short*)d_ws;
    wtrans2_kernel<<<128, 256, 0, stream>>>(w, wt2);
    conv_fused_kernel<<<NTILE, 256, 0, stream>>>(x, wt2, bias, out);
  } else {
    conv2d_f32_kernel<<<dim3(13, OC_ / 8, B_), 256, 0, stream>>>(x, w, bias, out);
  }
}